// Round 2
// baseline (293.094 us; speedup 1.0000x reference)
//
#include <hip/hip_runtime.h>
#include <hip/hip_bf16.h>
#include <math.h>

#define N_NODES 80000
#define N_EDGES 1280000
#define IN_C 128
#define HID_C 64
#define OUT_C 40

#define KB 313            // ceil(80000 / 256) bucket count (block-sum granularity)
#define HB 160            // histogram blocks in the merged hist|gemm1 launch
#define NBLK_G1 625       // N_NODES / 128 (8 waves x 16 nodes per block)

// ---- bf16 helpers (storage bf16, math fp32) ----
__device__ __forceinline__ float bf_lo(unsigned u) {
    union { unsigned i; float f; } c; c.i = u << 16; return c.f;
}
__device__ __forceinline__ float bf_hi(unsigned u) {
    union { unsigned i; float f; } c; c.i = u & 0xffff0000u; return c.f;
}
__device__ __forceinline__ unsigned pack_bf2(float a, float b) {  // RTNE
    union { float f; unsigned i; } ca, cb; ca.f = a; cb.f = b;
    unsigned ra = (ca.i + 0x7fffu + ((ca.i >> 16) & 1u)) >> 16;
    unsigned rb = (cb.i + 0x7fffu + ((cb.i >> 16) & 1u)) >> 16;
    return ra | (rb << 16);
}

typedef short v8s __attribute__((ext_vector_type(8)));   // 8 bf16 = 4 VGPR
typedef float v4f __attribute__((ext_vector_type(4)));
typedef float v2f __attribute__((ext_vector_type(2)));
union U16 { uint4 u; v8s s; };

__device__ __forceinline__ v2f bf2f(unsigned u) {        // unpack pair -> float2
    return (v2f){bf_lo(u), bf_hi(u)};
}

// ======== prep: W1^T, W2^T to bf16 + zero deg/bsum (313 blocks) ========
__global__ void prep_w_kernel(const float* __restrict__ W1, const float* __restrict__ W2,
                              unsigned* __restrict__ w1t, unsigned* __restrict__ w2t,
                              int* __restrict__ deg, int* __restrict__ bsum) {
    const int g = blockIdx.x * 256 + threadIdx.x;     // 0..80127
    if (g < N_NODES) deg[g] = 0;
    if (g < KB) bsum[g] = 0;
    if (g < 4096) {   // w1t
        const int wcol = g >> 6, kk = g & 63;
        w1t[g] = pack_bf2(W1[(2 * kk) * HID_C + wcol], W1[(2 * kk + 1) * HID_C + wcol]);
    }
    if (g < 1536) {   // w2t
        const int wcol = g >> 5, kk = g & 31;
        w2t[g] = (wcol < OUT_C)
            ? pack_bf2(W2[(2 * kk) * OUT_C + wcol], W2[(2 * kk + 1) * OUT_C + wcol])
            : 0u;
    }
}

// ===== Combined launch: blocks [0,HB) build degree histogram; rest do GEMM1 =====
// hist: global atomicAdd per edge on deg[80000] (L2 atomics, ~16/counter) +
// per-block LDS 313-bucket histogram flushed to bsum (block-sum for the scan).
// GEMM1 blocks carry only 1.25 KB LDS -> full occupancy; both jobs overlap.
__global__ __launch_bounds__(512) void hist_gemm1_kernel(const int* __restrict__ dst,
                                                         int* __restrict__ deg,
                                                         int* __restrict__ bsum,
                                                         const float* __restrict__ x,
                                                         const unsigned* __restrict__ w1t,
                                                         unsigned* __restrict__ h1b) {
    if (blockIdx.x >= HB) {
        // ---------- GEMM1 (MFMA): h1b = bf16(x @ W1), 8 waves, 128 nodes/block ----------
        const int tid = threadIdx.x;
        const int wave = tid >> 6, lane = tid & 63;
        const int nl = lane & 15, quad = lane >> 4;
        const int node = ((blockIdx.x - HB) * 8 + wave) * 16 + nl;

        v4f acc[4];
#pragma unroll
        for (int q = 0; q < 4; ++q) acc[q] = (v4f){0.f, 0.f, 0.f, 0.f};

#pragma unroll
        for (int kit = 0; kit < 4; ++kit) {
            const float* xp = x + (size_t)node * IN_C + kit * 32 + quad * 8;
            const float4 lo = *(const float4*)xp;
            const float4 hi = *(const float4*)(xp + 4);
            U16 bu;
            bu.u.x = pack_bf2(lo.x, lo.y); bu.u.y = pack_bf2(lo.z, lo.w);
            bu.u.z = pack_bf2(hi.x, hi.y); bu.u.w = pack_bf2(hi.z, hi.w);
#pragma unroll
            for (int mt = 0; mt < 4; ++mt) {
                U16 au;
                au.u = *(const uint4*)(w1t + ((mt * 16 + nl) * 64 + kit * 16 + quad * 4));
                acc[mt] = __builtin_amdgcn_mfma_f32_16x16x32_bf16(au.s, bu.s, acc[mt], 0, 0, 0);
            }
        }
#pragma unroll
        for (int mt = 0; mt < 4; ++mt) {
            uint2 o;
            o.x = pack_bf2(acc[mt][0], acc[mt][1]);
            o.y = pack_bf2(acc[mt][2], acc[mt][3]);
            *(uint2*)(h1b + (size_t)node * 32 + mt * 8 + quad * 2) = o;
        }
        return;
    }

    // ---------- degree histogram ----------
    __shared__ int lh[KB];
    const int tid = threadIdx.x;
    for (int i = tid; i < KB; i += 512) lh[i] = 0;
    __syncthreads();

    const int4* __restrict__ d4 = (const int4*)dst;
    for (int i = blockIdx.x * 512 + tid; i < N_EDGES / 4; i += HB * 512) {
        const int4 d = d4[i];
        atomicAdd(&deg[d.x], 1); atomicAdd(&lh[d.x >> 8], 1);
        atomicAdd(&deg[d.y], 1); atomicAdd(&lh[d.y >> 8], 1);
        atomicAdd(&deg[d.z], 1); atomicAdd(&lh[d.z >> 8], 1);
        atomicAdd(&deg[d.w], 1); atomicAdd(&lh[d.w >> 8], 1);
    }
    __syncthreads();
    for (int i = tid; i < KB; i += 512)
        if (lh[i]) atomicAdd(&bsum[i], lh[i]);
}

// ===== scan_fin: rp = exclusive_scan(deg); cur = rp copy (for scatter) =====
// Each block: redundant LDS scan of bsum (313) -> its block offset, then local
// 256-element scan of its degrees -> final rp in one pass. rp[80000]=N_EDGES falls
// out naturally at b=312 (out-of-range nodes contribute degree 0).
__global__ __launch_bounds__(512) void scan_fin_kernel(const int* __restrict__ deg,
                                                       const int* __restrict__ bsum,
                                                       int* __restrict__ rp,
                                                       int* __restrict__ cur) {
    __shared__ int sb[KB];
    __shared__ int sd[256];
    const int b = blockIdx.x, tid = threadIdx.x;

    if (tid < KB) sb[tid] = bsum[tid];
    __syncthreads();
    for (int o = 1; o < KB; o <<= 1) {
        int t = (tid < KB && tid >= o) ? sb[tid - o] : 0;
        __syncthreads();
        if (tid < KB) sb[tid] += t;
        __syncthreads();
    }
    const int boff = (b == 0) ? 0 : sb[b - 1];

    const int node = b * 256 + tid;
    int d = 0;
    if (tid < 256 && node < N_NODES) d = deg[node];
    if (tid < 256) sd[tid] = d;
    __syncthreads();
    for (int o = 1; o < 256; o <<= 1) {
        int t = (tid < 256 && tid >= o) ? sd[tid - o] : 0;
        __syncthreads();
        if (tid < 256) sd[tid] += t;
        __syncthreads();
    }
    if (tid < 256 && node <= N_NODES) {
        const int v = boff + sd[tid] - d;   // exclusive
        rp[node] = v;
        if (node < N_NODES) cur[node] = v;
    }
}

// ===== scatter: col[atomicAdd(&cur[dst],1)] = src — one-shot, int4 edge loads =====
__global__ __launch_bounds__(512) void scatter_kernel(const int* __restrict__ src,
                                                      const int* __restrict__ dst,
                                                      int* __restrict__ cur,
                                                      int* __restrict__ col) {
    const int i = blockIdx.x * 512 + threadIdx.x;   // 625*512 = 320000 = N_EDGES/4
    const int4 s = ((const int4*)src)[i];
    const int4 d = ((const int4*)dst)[i];
    col[atomicAdd(&cur[d.x], 1)] = s.x;
    col[atomicAdd(&cur[d.y], 1)] = s.y;
    col[atomicAdd(&cur[d.z], 1)] = s.z;
    col[atomicAdd(&cur[d.w], 1)] = s.w;
}

// ===== SpMM1 gather + fused GEMM2: block = 16 nodes (512 thr, 8 waves). =====
// Gather: 2 nodes/wave, 32 lanes/node: 4 edge slots x 8 lanes x uint4; idx from LDS.
// Epilogue: relu'd bf16 agg rows staged in LDS (stride 36 u32 -> conflict-free),
// wave 0 runs the 64x40 MFMA GEMM and writes fp8 h2f directly (agg never hits HBM).
__global__ __launch_bounds__(512) void gather64_g2_kernel(const int* __restrict__ rp,
                                                          const int* __restrict__ col,
                                                          const unsigned* __restrict__ h1b,
                                                          const unsigned* __restrict__ w2t,
                                                          unsigned* __restrict__ h2f) {
    __shared__ int lcol[1536];         // mean 256 edges/16 nodes, 1536 = +80 sigma
    __shared__ unsigned aggLds[16 * 36];  // 16 nodes x 32 u32, padded to 36 (16B-aligned)
    const int tid = threadIdx.x;
    const int lane = tid & 63;
    const int wave = tid >> 6;
    const int sl = lane & 31;          // sub-lane within node group
    const int es = sl >> 3;            // edge slot 0..3
    const int cl = sl & 7;             // channel group (uint4 = 8 ch)
    const int nb = blockIdx.x * 16;

    const int seg_b = rp[nb];
    const int seg_n = min(rp[nb + 16] - seg_b, 1536);
    for (int i = tid; i < seg_n; i += 512) lcol[i] = col[seg_b + i];
    __syncthreads();

    const int nloc = wave * 2 + (lane >> 5);
    const int node = nb + nloc;
    const int b = rp[node], e = rp[node + 1];

    v2f acc[4];
#pragma unroll
    for (int k = 0; k < 4; ++k) acc[k] = (v2f){0.f, 0.f};

    for (int pos = b; __any(pos < e); pos += 32) {
#pragma unroll
        for (int j = 0; j < 8; ++j) {
            const int ei = pos + (j << 2) + es;
            if (ei < e) {
                const int o = ei - seg_b;
                const int s = (o < seg_n) ? lcol[o] : col[ei];
                const uint4 v = *(const uint4*)(h1b + (size_t)s * 32 + cl * 4);
                acc[0] += bf2f(v.x); acc[1] += bf2f(v.y);
                acc[2] += bf2f(v.z); acc[3] += bf2f(v.w);
            }
        }
    }
    // fold 4 edge-slots -> slot 0 (lanes sl<8), within each 32-lane group
#pragma unroll
    for (int k = 0; k < 4; ++k) {
        acc[k][0] += __shfl_down(acc[k][0], 16, 64);
        acc[k][1] += __shfl_down(acc[k][1], 16, 64);
    }
#pragma unroll
    for (int k = 0; k < 4; ++k) {
        acc[k][0] += __shfl_down(acc[k][0], 8, 64);
        acc[k][1] += __shfl_down(acc[k][1], 8, 64);
    }

    if (sl < 8) {   // relu fused (agg only feeds relu->W2); same bf16 pack as before
        uint4 o;
        o.x = pack_bf2(fmaxf(acc[0][0], 0.f), fmaxf(acc[0][1], 0.f));
        o.y = pack_bf2(fmaxf(acc[1][0], 0.f), fmaxf(acc[1][1], 0.f));
        o.z = pack_bf2(fmaxf(acc[2][0], 0.f), fmaxf(acc[2][1], 0.f));
        o.w = pack_bf2(fmaxf(acc[3][0], 0.f), fmaxf(acc[3][1], 0.f));
        *(uint4*)(aggLds + nloc * 36 + cl * 4) = o;
    }
    __syncthreads();

    // ---- fused GEMM2 (wave 0 only): h2f = fp8(aggLds @ W2), 16 nodes ----
    if (wave == 0) {
        const int nl = lane & 15, quad = lane >> 4;
        v4f c[3];
#pragma unroll
        for (int q = 0; q < 3; ++q) c[q] = (v4f){0.f, 0.f, 0.f, 0.f};

#pragma unroll
        for (int kit = 0; kit < 2; ++kit) {
            U16 bu;
            bu.u = *(const uint4*)(aggLds + nl * 36 + kit * 16 + quad * 4);
#pragma unroll
            for (int mt = 0; mt < 3; ++mt) {
                U16 au;
                au.u = *(const uint4*)(w2t + ((mt * 16 + nl) * 32 + kit * 16 + quad * 4));
                c[mt] = __builtin_amdgcn_mfma_f32_16x16x32_bf16(au.s, bu.s, c[mt], 0, 0, 0);
            }
        }
        const int node2 = nb + nl;
#pragma unroll
        for (int mt = 0; mt < 3; ++mt) {
            const int idx = mt * 4 + quad;
            if (idx < 10) {
                int u = 0;
                u = __builtin_amdgcn_cvt_pk_fp8_f32(c[mt][0], c[mt][1], u, false);
                u = __builtin_amdgcn_cvt_pk_fp8_f32(c[mt][2], c[mt][3], u, true);
                h2f[(size_t)node2 * 10 + idx] = (unsigned)u;
            }
        }
    }
}

// ==== SpMM2 gather + log_softmax: fp8 table; block = 16 nodes, LDS col staging ====
// 4 nodes/wave, 16 lanes/node: 3 edge slots x 5 lanes x uint2 (8 fp8 ch).
__global__ void gather40_ls_kernel(const int* __restrict__ rp, const int* __restrict__ col,
                                   const unsigned* __restrict__ h2f,
                                   float* __restrict__ out) {
    __shared__ int lcol[1024];         // mean 256, 1024 = +48 sigma
    const int tid = threadIdx.x;
    const int lane = tid & 63;
    const int wave = tid >> 6;
    const int sl = lane & 15;
    const int es = sl / 5;            // 0..3 (es==3: lane 15 idle for loads)
    const int cl = sl - es * 5;       // 0..4 (uint2 = 8 fp8 ch)
    const int gbase = lane & 48;      // group base lane (g*16)
    const int nb = blockIdx.x * 16;

    const int seg_b = rp[nb];
    const int seg_n = min(rp[nb + 16] - seg_b, 1024);
    for (int i = tid; i < seg_n; i += 256) lcol[i] = col[seg_b + i];
    __syncthreads();

    const int node = nb + wave * 4 + (lane >> 4);
    const int b = rp[node], e = rp[node + 1];

    v2f a[4];
#pragma unroll
    for (int k = 0; k < 4; ++k) a[k] = (v2f){0.f, 0.f};

    for (int pos = b; __any(pos < e); pos += 24) {
#pragma unroll
        for (int j = 0; j < 8; ++j) {
            const int ei = pos + j * 3 + es;
            if ((es < 3) && (ei < e)) {
                const int o = ei - seg_b;
                const int s = (o < seg_n) ? lcol[o] : col[ei];
                const uint2 v = *(const uint2*)(h2f + (size_t)s * 10 + cl * 2);
                a[0] += __builtin_amdgcn_cvt_pk_f32_fp8((int)v.x, false);
                a[1] += __builtin_amdgcn_cvt_pk_f32_fp8((int)v.x, true);
                a[2] += __builtin_amdgcn_cvt_pk_f32_fp8((int)v.y, false);
                a[3] += __builtin_amdgcn_cvt_pk_f32_fp8((int)v.y, true);
            }
        }
    }
    // fold 3 edge-slots -> lanes sl<5 within each 16-lane group
#pragma unroll
    for (int k = 0; k < 4; ++k) {
#pragma unroll
        for (int h = 0; h < 2; ++h) {
            const float u = __shfl_down(a[k][h], 5, 64);
            const float w = __shfl_down(a[k][h], 10, 64);
            a[k][h] += u + w;
        }
    }

    const bool own = sl < 5;
    float m = -INFINITY;
    if (own) {
#pragma unroll
        for (int k = 0; k < 4; ++k) m = fmaxf(m, fmaxf(a[k][0], a[k][1]));
    }
    const float m0 = __shfl(m, gbase + 0, 64), m1 = __shfl(m, gbase + 1, 64);
    const float m2 = __shfl(m, gbase + 2, 64), m3 = __shfl(m, gbase + 3, 64);
    const float m4 = __shfl(m, gbase + 4, 64);
    const float gm = fmaxf(fmaxf(fmaxf(m0, m1), fmaxf(m2, m3)), m4);

    float s = 0.f;
    if (own) {
#pragma unroll
        for (int k = 0; k < 4; ++k)
            s += __expf(a[k][0] - gm) + __expf(a[k][1] - gm);
    }
    const float s0 = __shfl(s, gbase + 0, 64), s1 = __shfl(s, gbase + 1, 64);
    const float s2 = __shfl(s, gbase + 2, 64), s3 = __shfl(s, gbase + 3, 64);
    const float s4 = __shfl(s, gbase + 4, 64);
    const float ls = __logf(s0 + s1 + s2 + s3 + s4) + gm;

    if (own) {
        float* op = out + (size_t)node * OUT_C + cl * 8;
        *(float4*)op = make_float4(a[0][0] - ls, a[0][1] - ls, a[1][0] - ls, a[1][1] - ls);
        *(float4*)(op + 4) = make_float4(a[2][0] - ls, a[2][1] - ls, a[3][0] - ls, a[3][1] - ls);
    }
}

extern "C" void kernel_launch(void* const* d_in, const int* in_sizes, int n_in,
                              void* d_out, int out_size, void* d_ws, size_t ws_size,
                              hipStream_t stream) {
    const float* x  = (const float*)d_in[0];
    const int* eidx = (const int*)d_in[1];
    const float* W1 = (const float*)d_in[2];
    const float* W2 = (const float*)d_in[3];
    float* out = (float*)d_out;

    const int* src = eidx;             // edge_index[0]
    const int* dst = eidx + N_EDGES;   // edge_index[1]

    // Workspace (u32 units; sizes padded to multiples of 4 for 16B alignment):
    //   h1b  [80000*32] 10.24 MB (bf16, node-major)
    //   h2f  [80000*10]  3.20 MB (fp8 e4m3)
    //   col  [1.28M], rp [80004], deg [80000], cur [80000], bsum [316], w1t, w2t
    unsigned* h1b  = (unsigned*)d_ws;
    unsigned* h2f  = h1b + (size_t)N_NODES * 32;
    int*      col  = (int*)(h2f + (size_t)N_NODES * 10);
    int*      rp   = col + N_EDGES;
    int*      deg  = rp + 80004;
    int*      cur  = deg + N_NODES;
    int*      bsum = cur + N_NODES;
    unsigned* w1t  = (unsigned*)(bsum + 316);
    unsigned* w2t  = w1t + 4096;

    // --- prep (+zero deg/bsum), overlapped {degree hist | GEMM1}, scan, scatter ---
    prep_w_kernel<<<313, 256, 0, stream>>>(W1, W2, w1t, w2t, deg, bsum);
    hist_gemm1_kernel<<<HB + NBLK_G1, 512, 0, stream>>>(dst, deg, bsum, x, w1t, h1b);
    scan_fin_kernel<<<KB, 512, 0, stream>>>(deg, bsum, rp, cur);
    scatter_kernel<<<N_EDGES / 4 / 512, 512, 0, stream>>>(src, dst, cur, col);

    // --- gather1 + fused GEMM2, then gather2 + log_softmax ---
    gather64_g2_kernel<<<N_NODES / 16, 512, 0, stream>>>(rp, col, h1b, w2t, h2f);
    gather40_ls_kernel<<<N_NODES / 16, 256, 0, stream>>>(rp, col, h2f, out);
}